// Round 13
// baseline (54.353 us; speedup 1.0000x reference)
//
#include <hip/hip_runtime.h>
#include <hip/hip_bf16.h>

#define N_DIM   3072
#define BATCH_N 8192
#define K_FIX   30

typedef __attribute__((ext_vector_type(8)))  short short8v;   // 8 bf16
typedef __attribute__((ext_vector_type(16))) float f32x16;

#define CG     32
#define NCG    (N_DIM / CG)          // 96 col groups
#define BCOLS  256                   // out cols per block (8 waves)
#define NCT    (N_DIM / BCOLS)       // 12 col tiles
#define CROWS  32                    // rows per chunk
#define NCH    4                     // chunks per block -> 128 rows/block
#define NRB    (BATCH_N / (CROWS * NCH))  // 64 row-blocks
#define PGRAN  80                    // LDS granules (16B) per row
#define NGRAN  (CROWS * PGRAN)       // 2560 granules per buffer
#define BTAB_BYTES (NCG * 4 * 64 * sizeof(short8v))   // 393,216 B

static __device__ __forceinline__ short bfs(float f) {
    __hip_bfloat16 h = __float2bfloat16(f);
    return __builtin_bit_cast(short, h);
}

static __device__ __forceinline__ short8v pack8(const float4 a, const float4 b) {
    short8v r;
    r[0] = bfs(a.x); r[1] = bfs(a.y); r[2] = bfs(a.z); r[3] = bfs(a.w);
    r[4] = bfs(b.x); r[5] = bfs(b.y); r[6] = bfs(b.z); r[7] = bfs(b.w);
    return r;
}

// ---- B-fragment build (band of W^T) ----
static __device__ __forceinline__ short8v build_bfrag(
    const float* __restrict__ V, int cg0, int j, int hi, int step)
{
    short8v v8;
    #pragma unroll
    for (int jj = 0; jj < 8; ++jj) {
        const int k = 16 * step + hi * 8 + jj;
        const int i = j + 32 - k;
        short v = 0;
        if (i >= 0 && i < K_FIX) {
            int c = cg0 - 32 + k;
            if (c < 0) c += N_DIM;
            v = bfs(V[(size_t)i * N_DIM + c]);
        }
        v8[jj] = v;
    }
    return v8;
}

// ---------------- pre-kernel: materialize B-fragment table into d_ws --------
__global__ __launch_bounds__(64)
void build_btab(const float* __restrict__ V, const int* __restrict__ dp,
                short8v* __restrict__ btab)
{
    bool ok = true;
    #pragma unroll
    for (int i = 0; i < K_FIX; ++i) ok = ok && (dp[i] == i);
    if (!ok) return;

    const int cgi  = (int)blockIdx.x;
    const int lane = (int)threadIdx.x;
    const int j    = lane & 31;
    const int hi   = lane >> 5;
    const int cg0  = cgi * CG;
    #pragma unroll
    for (int step = 0; step < 4; ++step)
        btab[(cgi * 4 + step) * 64 + lane] = build_bfrag(V, cg0, j, hi, step);
}

// ---------------- Path 1: pipelined multi-chunk MFMA band-GEMM --------------
// R12 post-mortem: dur pinned at ~58us across 3 staging schemes; the model
// that fits is total L2/L3/HBM traffic ~320 MB at ~5.5 TB/s effective.  The
// biggest cuttable term was btab re-read (98 MB: 4 KB per one-shot wave).
// R13: each block does NCH=4 row-chunks (256 cols x 128 rows); Bf loaded
// ONCE per wave (btab 98->24 MB); x staged per-chunk into double-buffered
// LDS via global_load_lds with counted-vmcnt pipelining: raw s_barrier (NOT
// __syncthreads -- that drains vmcnt(0), the m97 stall), stage(c+2) issued
// right after the read-barrier, vmcnt(21)/(16) lets 5 loads + 16 stores stay
// in flight across barriers.  Compute/store path is bit-identical to R12
// (verified absmax 0.125 since R6).
#define SFENCE() __builtin_amdgcn_sched_barrier(0)
#define SBAR()  do { SFENCE(); __builtin_amdgcn_s_barrier(); SFENCE(); } while (0)
#define VMCNT(n) do { SFENCE(); \
    asm volatile("s_waitcnt vmcnt(" #n ")" ::: "memory"); SFENCE(); } while (0)

template<bool USE_TAB>
__global__ __launch_bounds__(512)
void fc_diag_pipe(const float* __restrict__ x, const float* __restrict__ V,
                  const int* __restrict__ dp, const short8v* __restrict__ btab,
                  float* __restrict__ out)
{
    bool ok = true;
    #pragma unroll
    for (int i = 0; i < K_FIX; ++i) ok = ok && (dp[i] == i);
    if (!ok) return;                 // block-uniform

    __shared__ float Xs[2 * NGRAN * 4];      // 2 x 40,960 B

    const int tid   = (int)threadIdx.x;
    const int lane  = tid & 63;
    const int wv    = tid >> 6;              // 8 waves
    const int ctile = (int)blockIdx.x % NCT;
    const int rblk  = (int)blockIdx.x / NCT;
    const int C0 = ctile * BCOLS;
    const int b0 = rblk * (CROWS * NCH);
    const int cgi = ctile * 8 + wv;
    const int j    = lane & 31;
    const int hi   = lane >> 5;

    // ---- B fragments: 4 coalesced loads, ONCE per wave (amortized x4) ----
    short8v Bf[4];
    if (USE_TAB) {
        const short8v* bt = btab + (size_t)cgi * 4 * 64 + lane;
        #pragma unroll
        for (int step = 0; step < 4; ++step)
            Bf[step] = bt[(size_t)step * 64];
    } else {
        #pragma unroll
        for (int step = 0; step < 4; ++step)
            Bf[step] = build_bfrag(V, cgi * CG, j, hi, step);
    }

    // ---- per-lane staging geometry (same verified swizzled source as R12):
    // granule G = (wv*5+u)*64 + lane; row = G/80, slot = G%80;
    // source col = C0 - 32 + 4*(slot ^ (row&15)), wrapped mod N.
    int srow[5], scol[5];
    #pragma unroll
    for (int u = 0; u < 5; ++u) {
        const int G = (wv * 5 + u) * 64 + lane;
        const int row = G / PGRAN;
        const int slot = G - row * PGRAN;
        int c = C0 - 32 + 4 * (slot ^ (row & 15));
        if (c < 0)      c += N_DIM;
        if (c >= N_DIM) c -= N_DIM;
        srow[u] = row; scol[u] = c;
    }

#define STAGE(c, s)                                                            \
    { _Pragma("unroll")                                                        \
      for (int u = 0; u < 5; ++u) {                                            \
          const int Gbase = (wv * 5 + u) * 64;                                 \
          const float* gp = x + (size_t)(b0 + (c) * CROWS + srow[u]) * N_DIM   \
                              + scol[u];                                       \
          __builtin_amdgcn_global_load_lds(                                    \
              (const __attribute__((address_space(1))) unsigned int*)gp,       \
              (__attribute__((address_space(3))) unsigned int*)                \
                  &Xs[(s) * (NGRAN * 4) + Gbase * 4],                          \
              16, 0, 0);                                                       \
      } }

#define COMPUTE(c, s)                                                          \
    { const float* xb = &Xs[(s) * (NGRAN * 4)];                                \
      f32x16 acc = {0.f,0.f,0.f,0.f, 0.f,0.f,0.f,0.f,                          \
                    0.f,0.f,0.f,0.f, 0.f,0.f,0.f,0.f};                         \
      const int gb = wv * 8 + hi * 2;                                          \
      _Pragma("unroll")                                                        \
      for (int step = 0; step < 4; ++step) {                                   \
          const int g0 = (gb + 4 * step + 0) ^ (j & 15);                       \
          const int g1 = (gb + 4 * step + 1) ^ (j & 15);                       \
          const float4 h0 = *reinterpret_cast<const float4*>(                  \
              xb + (j * PGRAN + g0) * 4);                                      \
          const float4 h1 = *reinterpret_cast<const float4*>(                  \
              xb + (j * PGRAN + g1) * 4);                                      \
          acc = __builtin_amdgcn_mfma_f32_32x32x16_bf16(                       \
              pack8(h0, h1), Bf[step], acc, 0, 0, 0);                          \
      }                                                                        \
      float* ob = out + (size_t)(b0 + (c) * CROWS) * N_DIM + C0 + wv * 32 + j; \
      _Pragma("unroll")                                                        \
      for (int reg = 0; reg < 16; ++reg) {                                     \
          const int row = (reg & 3) + 8 * (reg >> 2) + 4 * hi;                 \
          ob[(size_t)row * N_DIM] = acc[reg];                                  \
      } }

    // ---- prologue: fill both buffers, loads for chunk1 stay in flight ----
    STAGE(0, 0);                 // vmem ops: [btab 4][stage0 5][stage1 5]
    STAGE(1, 1);
    VMCNT(5);                    // btab + stage0 complete (allow stage1)
    SBAR();

    COMPUTE(0, 0);               // +16 stores
    SBAR();                      // all waves done reading buf0
    STAGE(2, 0);
    VMCNT(21);                   // stage1 complete (allow 16 stores + stage2)
    SBAR();

    COMPUTE(1, 1);
    SBAR();
    STAGE(3, 1);
    VMCNT(21);                   // stage2 complete
    SBAR();

    COMPUTE(2, 0);
    VMCNT(16);                   // stage3 complete (allow cmp2's 16 stores)
    SBAR();

    COMPUTE(3, 1);
#undef STAGE
#undef COMPUTE
}

// ---------------- Path 2: general K=30 (arbitrary diag values) --------------
#define G_NBT   128
#define G_BROWS (BATCH_N / G_NBT)    // 64

__global__ __launch_bounds__(256)
void fc_diag_general30(const float* __restrict__ x, const float* __restrict__ V,
                       const int* __restrict__ dp, float* __restrict__ out)
{
    bool contig = true;
    #pragma unroll
    for (int i = 0; i < K_FIX; ++i) contig = contig && (dp[i] == i);
    if (contig) return;  // fast kernel handled it

    const int NRT2 = N_DIM / 256;
    const int rtile = blockIdx.x % NRT2;
    const int btile = blockIdx.x / NRT2;
    const int r  = rtile * 256 + (int)threadIdx.x;
    const int b0 = btile * G_BROWS;

    int   CI[K_FIX];
    float VW[K_FIX];
    #pragma unroll
    for (int i = 0; i < K_FIX; ++i) {
        int d = dp[i] % N_DIM; if (d < 0) d += N_DIM;
        int c = r - d; if (c < 0) c += N_DIM;
        CI[i] = c;
        VW[i] = V[(size_t)d * N_DIM + c];
    }

    for (int b = b0; b < b0 + G_BROWS; b += 2) {
        const float* xb0 = x + (size_t)b * N_DIM;
        const float* xb1 = xb0 + N_DIM;
        float a0 = 0.f, a1 = 0.f;
        #pragma unroll
        for (int i = 0; i < K_FIX; ++i) {
            const float w = VW[i]; const int c = CI[i];
            a0 = fmaf(xb0[c], w, a0);
            a1 = fmaf(xb1[c], w, a1);
        }
        out[(size_t)b * N_DIM + r]       = a0;
        out[(size_t)(b + 1) * N_DIM + r] = a1;
    }
}

// ---------------- Path 3: naive fallback for K != 30 ------------------------
__global__ void fc_diag_naive(const float* __restrict__ x, const float* __restrict__ V,
                              const int* __restrict__ dp, int K, float* __restrict__ out)
{
    size_t idx   = (size_t)blockIdx.x * blockDim.x + threadIdx.x;
    size_t total = (size_t)BATCH_N * N_DIM;
    size_t step  = (size_t)gridDim.x * blockDim.x;
    for (; idx < total; idx += step) {
        int b = (int)(idx / N_DIM), r = (int)(idx % N_DIM);
        float acc = 0.f;
        for (int i = 0; i < K; ++i) {
            int d = dp[i] % N_DIM; if (d < 0) d += N_DIM;
            int c = r - d; if (c < 0) c += N_DIM;
            acc = fmaf(x[(size_t)b * N_DIM + c], V[(size_t)d * N_DIM + c], acc);
        }
        out[idx] = acc;
    }
}

extern "C" void kernel_launch(void* const* d_in, const int* in_sizes, int n_in,
                              void* d_out, int out_size, void* d_ws, size_t ws_size,
                              hipStream_t stream)
{
    const float* x  = (const float*)d_in[0];
    const float* V  = (const float*)d_in[1];
    const int*   dp = (const int*)d_in[2];
    float* out = (float*)d_out;
    const int K = in_sizes[2];

    if (K == K_FIX) {
        if (ws_size >= BTAB_BYTES) {
            short8v* btab = (short8v*)d_ws;
            build_btab<<<dim3(NCG), dim3(64), 0, stream>>>(V, dp, btab);
            fc_diag_pipe<true><<<dim3(NCT * NRB), dim3(512), 0, stream>>>(
                x, V, dp, btab, out);
        } else {
            fc_diag_pipe<false><<<dim3(NCT * NRB), dim3(512), 0, stream>>>(
                x, V, dp, nullptr, out);
        }
        fc_diag_general30<<<dim3((N_DIM / 256) * G_NBT), dim3(256), 0, stream>>>(x, V, dp, out);
    } else {
        fc_diag_naive<<<dim3(2048), dim3(256), 0, stream>>>(x, V, dp, K, out);
    }
}

// Round 14
// 53.873 us; speedup vs baseline: 1.0089x; 1.0089x over previous
//
#include <hip/hip_runtime.h>
#include <hip/hip_bf16.h>

#define N_DIM   3072
#define BATCH_N 8192
#define K_FIX   30

typedef __attribute__((ext_vector_type(8)))  short short8v;   // 8 bf16
typedef __attribute__((ext_vector_type(16))) float f32x16;

#define CG     32
#define NCG    (N_DIM / CG)          // 96 col groups
#define NCHW   8                     // chunks per wave
#define CROWS  32                    // rows per chunk
#define WROWS  (NCHW * CROWS)        // 256 rows per wave
#define NRG    (BATCH_N / WROWS)     // 32 row groups -> 3072 waves, 768 blocks
#define GR     16                    // granules (16B) per row (64 cols)
#define CHGRAN (CROWS * GR)          // 512 granules = 8 KB per chunk buffer
#define BTAB_BYTES (NCG * 4 * 64 * sizeof(short8v))   // 393,216 B

static __device__ __forceinline__ short bfs(float f) {
    __hip_bfloat16 h = __float2bfloat16(f);
    return __builtin_bit_cast(short, h);
}

static __device__ __forceinline__ short8v pack8(const float4 a, const float4 b) {
    short8v r;
    r[0] = bfs(a.x); r[1] = bfs(a.y); r[2] = bfs(a.z); r[3] = bfs(a.w);
    r[4] = bfs(b.x); r[5] = bfs(b.y); r[6] = bfs(b.z); r[7] = bfs(b.w);
    return r;
}

// ---- B-fragment build (band of W^T) ----
static __device__ __forceinline__ short8v build_bfrag(
    const float* __restrict__ V, int cg0, int j, int hi, int step)
{
    short8v v8;
    #pragma unroll
    for (int jj = 0; jj < 8; ++jj) {
        const int k = 16 * step + hi * 8 + jj;
        const int i = j + 32 - k;
        short v = 0;
        if (i >= 0 && i < K_FIX) {
            int c = cg0 - 32 + k;
            if (c < 0) c += N_DIM;
            v = bfs(V[(size_t)i * N_DIM + c]);
        }
        v8[jj] = v;
    }
    return v8;
}

// ---------------- pre-kernel: materialize B-fragment table into d_ws --------
__global__ __launch_bounds__(64)
void build_btab(const float* __restrict__ V, const int* __restrict__ dp,
                short8v* __restrict__ btab)
{
    bool ok = true;
    #pragma unroll
    for (int i = 0; i < K_FIX; ++i) ok = ok && (dp[i] == i);
    if (!ok) return;

    const int cgi  = (int)blockIdx.x;
    const int lane = (int)threadIdx.x;
    const int j    = lane & 31;
    const int hi   = lane >> 5;
    const int cg0  = cgi * CG;
    #pragma unroll
    for (int step = 0; step < 4; ++step)
        btab[(cgi * 4 + step) * 64 + lane] = build_bfrag(V, cg0, j, hi, step);
}

// ---------------- Path 1: per-wave pipelined MFMA band-GEMM -----------------
// R13 falsified the traffic-ceiling model (traffic -23%, dur +10%).  The
// surviving theory: one-shot/barrier-coupled waves serialize {load-drain ->
// compute}; nothing overlaps the drain.  R14: each wave owns 8 chunks and a
// PRIVATE double-buffered LDS slice (2 x 8 KB), staged via global_load_lds
// (no dest VGPRs, so the allocator cannot serialize issue) with counted
// vmcnt: stage(c+2) issues right after compute(c); vmcnt(24) before
// compute(c+1) retires exactly stage(c+1) while stage(c+2) + 16 stores stay
// in flight.  NO barriers, NO cross-wave coupling; within-wave LDS RAW is
// safe (gload_lds issues after the MFMAs that consumed the buffer executed).
// Swizzle: LDS linear; source granule = slot ^ (row&15); read slot =
// g ^ (j&15) -- the verified R12 involution (bit-identical output).
// C/D layout (m74/m101): col = lane&31, row = (reg&3)+8*(reg>>2)+4*(lane>>5).
#define SFENCE() __builtin_amdgcn_sched_barrier(0)
#define VMCNT(n) do { SFENCE(); \
    asm volatile("s_waitcnt vmcnt(" #n ")" ::: "memory"); SFENCE(); } while (0)

template<bool USE_TAB>
__global__ __launch_bounds__(256)
void fc_diag_pipe(const float* __restrict__ x, const float* __restrict__ V,
                  const int* __restrict__ dp, const short8v* __restrict__ btab,
                  float* __restrict__ out)
{
    bool ok = true;
    #pragma unroll
    for (int i = 0; i < K_FIX; ++i) ok = ok && (dp[i] == i);
    if (!ok) return;

    __shared__ float Xs[4 * 2 * CHGRAN * 4];     // 4 waves x 2 bufs x 8 KB

    const int lane = (int)threadIdx.x & 63;
    const int wv   = (int)threadIdx.x >> 6;
    const int gw   = (int)blockIdx.x * 4 + wv;
    const int cgi  = gw % NCG;        // adjacent waves -> adjacent col groups
    const int rgi  = gw / NCG;        //   (same rows: L1/L2 overlap reuse)
    const int cg0  = cgi * CG;
    const int b0   = rgi * WROWS;
    const int j    = lane & 31;       // out col within group / A row
    const int hi   = lane >> 5;

    // ---- B fragments: 4 coalesced loads, once per wave (amortized 8x) ----
    short8v Bf[4];
    if (USE_TAB) {
        const short8v* bt = btab + (size_t)cgi * 4 * 64 + lane;
        #pragma unroll
        for (int step = 0; step < 4; ++step)
            Bf[step] = bt[(size_t)step * 64];
    } else {
        #pragma unroll
        for (int step = 0; step < 4; ++step)
            Bf[step] = build_bfrag(V, cg0, j, hi, step);
    }

    // ---- per-lane staging geometry (chunk-invariant) ----
    // instr u: granule G = u*64 + lane; row = G/16, slot = G%16;
    // source col = cg0 - 32 + 4*(slot ^ (row&15)), wrapped mod N.
    int srow[8], scol[8];
    #pragma unroll
    for (int u = 0; u < 8; ++u) {
        const int G = u * 64 + lane;
        const int row = G >> 4;
        const int slot = G & 15;
        int c = cg0 - 32 + 4 * (slot ^ (row & 15));
        if (c < 0) c += N_DIM;
        srow[u] = row; scol[u] = c;
    }
    float* const myXs = &Xs[wv * 2 * CHGRAN * 4];

#define STAGE(ch, s)                                                           \
    { _Pragma("unroll")                                                        \
      for (int u = 0; u < 8; ++u) {                                            \
          const float* gp = x + (size_t)(b0 + (ch) * CROWS + srow[u]) * N_DIM  \
                              + scol[u];                                       \
          __builtin_amdgcn_global_load_lds(                                    \
              (const __attribute__((address_space(1))) unsigned int*)gp,       \
              (__attribute__((address_space(3))) unsigned int*)                \
                  (myXs + (s) * (CHGRAN * 4) + u * 256),                       \
              16, 0, 0);                                                       \
      } }

#define COMPUTE(ch, s)                                                         \
    { const float* xb = myXs + (s) * (CHGRAN * 4);                             \
      f32x16 acc = {0.f,0.f,0.f,0.f, 0.f,0.f,0.f,0.f,                          \
                    0.f,0.f,0.f,0.f, 0.f,0.f,0.f,0.f};                         \
      _Pragma("unroll")                                                        \
      for (int step = 0; step < 4; ++step) {                                   \
          const int g0 = (hi * 2 + 4 * step + 0) ^ (j & 15);                   \
          const int g1 = (hi * 2 + 4 * step + 1) ^ (j & 15);                   \
          const float4 h0 = *reinterpret_cast<const float4*>(                  \
              xb + (j * GR + g0) * 4);                                         \
          const float4 h1 = *reinterpret_cast<const float4*>(                  \
              xb + (j * GR + g1) * 4);                                         \
          acc = __builtin_amdgcn_mfma_f32_32x32x16_bf16(                       \
              pack8(h0, h1), Bf[step], acc, 0, 0, 0);                          \
      }                                                                        \
      float* ob = out + (size_t)(b0 + (ch) * CROWS) * N_DIM + cg0 + j;         \
      _Pragma("unroll")                                                        \
      for (int reg = 0; reg < 16; ++reg) {                                     \
          const int row = (reg & 3) + 8 * (reg >> 2) + 4 * hi;                 \
          ob[(size_t)row * N_DIM] = acc[reg];                                  \
      } }

#define WAIT_INIT() do { if constexpr (USE_TAB) VMCNT(8);  else VMCNT(0); } while (0)
#define WAIT_MID()  do { if constexpr (USE_TAB) VMCNT(24); else VMCNT(0); } while (0)
#define WAIT_TAIL() do { if constexpr (USE_TAB) VMCNT(16); else VMCNT(0); } while (0)

    // queue: [btab 4][st0 8][st1 8] -> vmcnt(8) retires btab + stage0
    STAGE(0, 0);
    STAGE(1, 1);
    WAIT_INIT();

    COMPUTE(0, 0); SFENCE(); STAGE(2, 0); WAIT_MID();
    COMPUTE(1, 1); SFENCE(); STAGE(3, 1); WAIT_MID();
    COMPUTE(2, 0); SFENCE(); STAGE(4, 0); WAIT_MID();
    COMPUTE(3, 1); SFENCE(); STAGE(5, 1); WAIT_MID();
    COMPUTE(4, 0); SFENCE(); STAGE(6, 0); WAIT_MID();
    COMPUTE(5, 1); SFENCE(); STAGE(7, 1); WAIT_MID();
    COMPUTE(6, 0); SFENCE(); WAIT_TAIL();
    COMPUTE(7, 1);

#undef STAGE
#undef COMPUTE
#undef WAIT_INIT
#undef WAIT_MID
#undef WAIT_TAIL
}

// ---------------- Path 2: general K=30 (arbitrary diag values) --------------
#define G_NBT   128
#define G_BROWS (BATCH_N / G_NBT)    // 64

__global__ __launch_bounds__(256)
void fc_diag_general30(const float* __restrict__ x, const float* __restrict__ V,
                       const int* __restrict__ dp, float* __restrict__ out)
{
    bool contig = true;
    #pragma unroll
    for (int i = 0; i < K_FIX; ++i) contig = contig && (dp[i] == i);
    if (contig) return;  // fast kernel handled it

    const int NRT2 = N_DIM / 256;
    const int rtile = blockIdx.x % NRT2;
    const int btile = blockIdx.x / NRT2;
    const int r  = rtile * 256 + (int)threadIdx.x;
    const int b0 = btile * G_BROWS;

    int   CI[K_FIX];
    float VW[K_FIX];
    #pragma unroll
    for (int i = 0; i < K_FIX; ++i) {
        int d = dp[i] % N_DIM; if (d < 0) d += N_DIM;
        int c = r - d; if (c < 0) c += N_DIM;
        CI[i] = c;
        VW[i] = V[(size_t)d * N_DIM + c];
    }

    for (int b = b0; b < b0 + G_BROWS; b += 2) {
        const float* xb0 = x + (size_t)b * N_DIM;
        const float* xb1 = xb0 + N_DIM;
        float a0 = 0.f, a1 = 0.f;
        #pragma unroll
        for (int i = 0; i < K_FIX; ++i) {
            const float w = VW[i]; const int c = CI[i];
            a0 = fmaf(xb0[c], w, a0);
            a1 = fmaf(xb1[c], w, a1);
        }
        out[(size_t)b * N_DIM + r]       = a0;
        out[(size_t)(b + 1) * N_DIM + r] = a1;
    }
}

// ---------------- Path 3: naive fallback for K != 30 ------------------------
__global__ void fc_diag_naive(const float* __restrict__ x, const float* __restrict__ V,
                              const int* __restrict__ dp, int K, float* __restrict__ out)
{
    size_t idx   = (size_t)blockIdx.x * blockDim.x + threadIdx.x;
    size_t total = (size_t)BATCH_N * N_DIM;
    size_t step  = (size_t)gridDim.x * blockDim.x;
    for (; idx < total; idx += step) {
        int b = (int)(idx / N_DIM), r = (int)(idx % N_DIM);
        float acc = 0.f;
        for (int i = 0; i < K; ++i) {
            int d = dp[i] % N_DIM; if (d < 0) d += N_DIM;
            int c = r - d; if (c < 0) c += N_DIM;
            acc = fmaf(x[(size_t)b * N_DIM + c], V[(size_t)d * N_DIM + c], acc);
        }
        out[idx] = acc;
    }
}

extern "C" void kernel_launch(void* const* d_in, const int* in_sizes, int n_in,
                              void* d_out, int out_size, void* d_ws, size_t ws_size,
                              hipStream_t stream)
{
    const float* x  = (const float*)d_in[0];
    const float* V  = (const float*)d_in[1];
    const int*   dp = (const int*)d_in[2];
    float* out = (float*)d_out;
    const int K = in_sizes[2];

    if (K == K_FIX) {
        if (ws_size >= BTAB_BYTES) {
            short8v* btab = (short8v*)d_ws;
            build_btab<<<dim3(NCG), dim3(64), 0, stream>>>(V, dp, btab);
            fc_diag_pipe<true><<<dim3(NCG * NRG / 4), dim3(256), 0, stream>>>(
                x, V, dp, btab, out);
        } else {
            fc_diag_pipe<false><<<dim3(NCG * NRG / 4), dim3(256), 0, stream>>>(
                x, V, dp, nullptr, out);
        }
        fc_diag_general30<<<dim3((N_DIM / 256) * G_NBT), dim3(256), 0, stream>>>(x, V, dp, out);
    } else {
        fc_diag_naive<<<dim3(2048), dim3(256), 0, stream>>>(x, V, dp, K, out);
    }
}

// Round 15
// 43.210 us; speedup vs baseline: 1.2579x; 1.2468x over previous
//
#include <hip/hip_runtime.h>
#include <hip/hip_bf16.h>

#define N_DIM   3072
#define BATCH_N 8192
#define K_FIX   30

typedef __attribute__((ext_vector_type(8)))  short short8v;   // 8 bf16
typedef __attribute__((ext_vector_type(16))) float f32x16;

#define CG     32
#define NCG    (N_DIM / CG)          // 96 col groups
#define BCOLS  256                   // out cols per block (8 waves)
#define NCT    (N_DIM / BCOLS)       // 12 col tiles
#define NRG    (BATCH_N / 32)        // 256 row tiles (32 rows per block)
#define PGRAN  80                    // LDS granules (16B) per row (320 cols)
#define NGRAN  (32 * PGRAN)          // 2560 granules per block
#define BTAB_BYTES (NCG * 4 * 64 * sizeof(short8v))   // 393,216 B

static __device__ __forceinline__ short bfs(float f) {
    __hip_bfloat16 h = __float2bfloat16(f);       // RNE
    return __builtin_bit_cast(short, h);
}

static __device__ __forceinline__ short8v pack8(const float4 a, const float4 b) {
    short8v r;
    r[0] = bfs(a.x); r[1] = bfs(a.y); r[2] = bfs(a.z); r[3] = bfs(a.w);
    r[4] = bfs(b.x); r[5] = bfs(b.y); r[6] = bfs(b.z); r[7] = bfs(b.w);
    return r;
}

// ---- B-fragment build (band of W^T) ----
// Bf[step][jj]: k = 16*step + hi*8 + jj, i = j + 32 - k, B = V[i][cg0-32+k].
static __device__ __forceinline__ short8v build_bfrag(
    const float* __restrict__ V, int cg0, int j, int hi, int step)
{
    short8v v8;
    #pragma unroll
    for (int jj = 0; jj < 8; ++jj) {
        const int k = 16 * step + hi * 8 + jj;
        const int i = j + 32 - k;
        short v = 0;
        if (i >= 0 && i < K_FIX) {
            int c = cg0 - 32 + k;
            if (c < 0) c += N_DIM;
            v = bfs(V[(size_t)i * N_DIM + c]);
        }
        v8[jj] = v;
    }
    return v8;
}

// ---------------- kernel 1: btab-build (contig) OR general30 (non-contig) ---
// Merging saves one launch (~2-4us of the replay).  contig: blocks < NCG
// build btab (tid = step*64+lane, 256 threads = 4 steps x 64 lanes), rest
// exit.  non-contig: full general fallback (never taken in this bench).
#define G_NBT   128
#define G_BROWS (BATCH_N / G_NBT)    // 64

__global__ __launch_bounds__(256)
void fc_prep_or_general(const float* __restrict__ x, const float* __restrict__ V,
                        const int* __restrict__ dp, short8v* __restrict__ btab,
                        int use_tab, float* __restrict__ out)
{
    bool contig = true;
    #pragma unroll
    for (int i = 0; i < K_FIX; ++i) contig = contig && (dp[i] == i);

    if (contig) {
        if (use_tab && (int)blockIdx.x < NCG) {
            const int cgi  = (int)blockIdx.x;
            const int step = (int)threadIdx.x >> 6;
            const int lane = (int)threadIdx.x & 63;
            btab[(cgi * 4 + step) * 64 + lane] =
                build_bfrag(V, cgi * CG, lane & 31, lane >> 5, step);
        }
        return;
    }

    // ---- general path: arbitrary diag values, K=30 ----
    const int NRT2 = N_DIM / 256;
    const int rtile = blockIdx.x % NRT2;
    const int btile = blockIdx.x / NRT2;
    const int r  = rtile * 256 + (int)threadIdx.x;
    const int b0 = btile * G_BROWS;

    int   CI[K_FIX];
    float VW[K_FIX];
    #pragma unroll
    for (int i = 0; i < K_FIX; ++i) {
        int d = dp[i] % N_DIM; if (d < 0) d += N_DIM;
        int c = r - d; if (c < 0) c += N_DIM;
        CI[i] = c;
        VW[i] = V[(size_t)d * N_DIM + c];
    }

    for (int b = b0; b < b0 + G_BROWS; b += 2) {
        const float* xb0 = x + (size_t)b * N_DIM;
        const float* xb1 = xb0 + N_DIM;
        float a0 = 0.f, a1 = 0.f;
        #pragma unroll
        for (int i = 0; i < K_FIX; ++i) {
            const float w = VW[i]; const int c = CI[i];
            a0 = fmaf(xb0[c], w, a0);
            a1 = fmaf(xb1[c], w, a1);
        }
        out[(size_t)b * N_DIM + r]       = a0;
        out[(size_t)(b + 1) * N_DIM + r] = a1;
    }
}

// ---------------- kernel 2: global_load_lds MFMA band-GEMM (R12, verified) --
// One 512-thread block = 8 waves x one 32x32 tile; 40KB LDS; coop stage via
// global_load_lds (linear LDS dest, inverse-XOR on the global source, rule
// #21); swizzled ds_read + 4 x mfma_f32_32x32x16_bf16; store layout m74/m101.
// CHANGE vs R12: ctile-major block order -- 256 consecutive blocks share one
// 32KB btab slice + one 10.5MB x column window, making those reads L2/L3-hot
// (R12's rtile-major spread 12 competing windows across the cache).
template<bool USE_TAB>
__global__ __launch_bounds__(512)
void fc_diag_mfma32(const float* __restrict__ x, const float* __restrict__ V,
                    const int* __restrict__ dp, const short8v* __restrict__ btab,
                    float* __restrict__ out)
{
    bool ok = true;
    #pragma unroll
    for (int i = 0; i < K_FIX; ++i) ok = ok && (dp[i] == i);
    if (!ok) return;                 // block-uniform: safe w.r.t. barrier

    __shared__ float Xs[NGRAN * 4];          // 40,960 B

    const int tid   = (int)threadIdx.x;
    const int lane  = tid & 63;
    const int wv    = tid >> 6;              // 8 waves
    const int ctile = (int)blockIdx.x / NRG;     // ctile-major (locality)
    const int rtile = (int)blockIdx.x % NRG;
    const int C0 = ctile * BCOLS;
    const int b0 = rtile * 32;
    const int cgi = ctile * 8 + wv;          // this wave's 32-col group
    const int j    = lane & 31;              // out col within group / A row
    const int hi   = lane >> 5;

    // ---- B fragments: 4 independent 16B loads (issued first) ----
    short8v Bf[4];
    if (USE_TAB) {
        const short8v* bt = btab + (size_t)cgi * 4 * 64 + lane;
        #pragma unroll
        for (int step = 0; step < 4; ++step)
            Bf[step] = bt[(size_t)step * 64];
    } else {
        #pragma unroll
        for (int step = 0; step < 4; ++step)
            Bf[step] = build_bfrag(V, cgi * CG, j, hi, step);
    }

    // ---- stage x tile via global_load_lds (no VGPR round-trip) ----
    // Wave wv covers granule chunks [(wv*5+u)*64, +64).  LDS dest linear
    // (HW adds lane*16); per-lane source: row = G/80, slot = G%80,
    // global granule = slot ^ (row&15), col wrapped mod N.
    #pragma unroll
    for (int u = 0; u < 5; ++u) {
        const int Gbase = (wv * 5 + u) * 64;
        const int G     = Gbase + lane;
        const int row   = G / PGRAN;
        const int slot  = G - row * PGRAN;
        int c = C0 - 32 + 4 * (slot ^ (row & 15));
        if (c < 0)       c += N_DIM;
        if (c >= N_DIM)  c -= N_DIM;
        const float* gp = x + (size_t)(b0 + row) * N_DIM + c;
        __builtin_amdgcn_global_load_lds(
            (const __attribute__((address_space(1))) unsigned int*)gp,
            (__attribute__((address_space(3))) unsigned int*)&Xs[Gbase * 4],
            16, 0, 0);
    }
    asm volatile("s_waitcnt vmcnt(0)" ::: "memory");
    __syncthreads();

    // ---- A frags from LDS + MFMA (verified R10-R12 path) ----
    // Wave wv needs logical granules wv*8 + hi*2 + 4*step + {0,1} of row j,
    // read at LDS slot g ^ (j&15), row stride 80 granules.
    f32x16 acc = {0.f,0.f,0.f,0.f, 0.f,0.f,0.f,0.f,
                  0.f,0.f,0.f,0.f, 0.f,0.f,0.f,0.f};
    const int gb = wv * 8 + hi * 2;
    #pragma unroll
    for (int step = 0; step < 4; ++step) {
        const int g0 = (gb + 4 * step + 0) ^ (j & 15);
        const int g1 = (gb + 4 * step + 1) ^ (j & 15);
        const float4 h0 = *reinterpret_cast<const float4*>(&Xs[(j * PGRAN + g0) * 4]);
        const float4 h1 = *reinterpret_cast<const float4*>(&Xs[(j * PGRAN + g1) * 4]);
        acc = __builtin_amdgcn_mfma_f32_32x32x16_bf16(pack8(h0, h1), Bf[step],
                                                      acc, 0, 0, 0);
    }

    // ---- store: col = j, row = (reg&3) + 8*(reg>>2) + 4*hi ----
    float* ob = out + (size_t)b0 * N_DIM + C0 + wv * 32 + j;
    #pragma unroll
    for (int reg = 0; reg < 16; ++reg) {
        const int row = (reg & 3) + 8 * (reg >> 2) + 4 * hi;
        ob[(size_t)row * N_DIM] = acc[reg];
    }
}

// ---------------- naive fallback for K != 30 --------------------------------
__global__ void fc_diag_naive(const float* __restrict__ x, const float* __restrict__ V,
                              const int* __restrict__ dp, int K, float* __restrict__ out)
{
    size_t idx   = (size_t)blockIdx.x * blockDim.x + threadIdx.x;
    size_t total = (size_t)BATCH_N * N_DIM;
    size_t step  = (size_t)gridDim.x * blockDim.x;
    for (; idx < total; idx += step) {
        int b = (int)(idx / N_DIM), r = (int)(idx % N_DIM);
        float acc = 0.f;
        for (int i = 0; i < K; ++i) {
            int d = dp[i] % N_DIM; if (d < 0) d += N_DIM;
            int c = r - d; if (c < 0) c += N_DIM;
            acc = fmaf(x[(size_t)b * N_DIM + c], V[(size_t)d * N_DIM + c], acc);
        }
        out[idx] = acc;
    }
}

extern "C" void kernel_launch(void* const* d_in, const int* in_sizes, int n_in,
                              void* d_out, int out_size, void* d_ws, size_t ws_size,
                              hipStream_t stream)
{
    const float* x  = (const float*)d_in[0];
    const float* V  = (const float*)d_in[1];
    const int*   dp = (const int*)d_in[2];
    float* out = (float*)d_out;
    const int K = in_sizes[2];

    if (K == K_FIX) {
        const int use_tab = (ws_size >= BTAB_BYTES) ? 1 : 0;
        short8v* btab = (short8v*)d_ws;
        // kernel 1: builds btab (contig) or computes general fallback
        fc_prep_or_general<<<dim3((N_DIM / 256) * G_NBT), dim3(256), 0, stream>>>(
            x, V, dp, btab, use_tab, out);
        // kernel 2: fast path (early-outs if non-contig)
        if (use_tab)
            fc_diag_mfma32<true><<<dim3(NCT * NRG), dim3(512), 0, stream>>>(
                x, V, dp, btab, out);
        else
            fc_diag_mfma32<false><<<dim3(NCT * NRG), dim3(512), 0, stream>>>(
                x, V, dp, nullptr, out);
    } else {
        fc_diag_naive<<<dim3(2048), dim3(256), 0, stream>>>(x, V, dp, K, out);
    }
}